// Round 7
// baseline (1285.243 us; speedup 1.0000x reference)
//
#include <hip/hip_runtime.h>

// Problem constants
#define BB 64
#define TT 4
#define NOBJ 6
#define RTOT 1536   // B*T*N
#define DD 256

typedef unsigned short ushort_t;
typedef __attribute__((ext_vector_type(8))) short short8_t;   // 8 bf16 (4 VGPRs)
typedef __attribute__((ext_vector_type(4))) float f32x4;

struct MatDesc { const float* src; float* dst; int kshift; int stride; int coff; };
struct MatDescs { MatDesc m[4]; };

#define FMA4(ACC, A4, W4) do { \
  ACC = fmaf((A4).x, (W4).x, ACC); \
  ACC = fmaf((A4).y, (W4).y, ACC); \
  ACC = fmaf((A4).z, (W4).z, ACC); \
  ACC = fmaf((A4).w, (W4).w, ACC); } while(0)

#define MFMA_BF16_16x16x32 __builtin_amdgcn_mfma_f32_16x16x32_bf16

__device__ __forceinline__ void split_bf16(float v, ushort_t& hs, ushort_t& ls) {
  unsigned int bits = __float_as_uint(v);
  hs = (ushort_t)(bits >> 16);
  float hf = __uint_as_float(bits & 0xFFFF0000u);
  ls = (ushort_t)(__float_as_uint(v - hf) >> 16);
}

// ---- single prep launch: y=0..3 WT transposes, y=4 small, y=5 rollout B-fragments ----
__global__ void prep_all(MatDescs md, const float* __restrict__ w1, const float* __restrict__ w2,
                         const float* __restrict__ rois, float* __restrict__ w1p,
                         ushort_t* __restrict__ w2fh, ushort_t* __restrict__ w2fl,
                         float* __restrict__ rbuf,
                         const float* __restrict__ g_self_w, const float* __restrict__ g_rel_w,
                         const float* __restrict__ g_aff_w, const float* __restrict__ g_out_w,
                         ushort_t* __restrict__ b1h, ushort_t* __restrict__ b1l,
                         ushort_t* __restrict__ bafh, ushort_t* __restrict__ bafl,
                         ushort_t* __restrict__ bouh, ushort_t* __restrict__ boul) {
  int y = blockIdx.y;
  int idx = blockIdx.x * 256 + threadIdx.x;
  if (y < 4) {
    const MatDesc de = md.m[y];
    int K = 1 << de.kshift;
    if (idx >= (256 << de.kshift)) return;
    int d = idx >> de.kshift;
    int kk = idx & (K - 1);
    de.dst[(kk >> 2) * 1024 + d * 4 + (kk & 3)] = de.src[d * de.stride + de.coff + kk];
  } else if (y == 4) {
    if (idx < 1728) w1p[idx] = w1[(idx & 63) * 27 + (idx >> 6)];
    int i2 = idx - 2048;
    if (i2 >= 0 && i2 < 36864) {
      int j = i2 & 7, lane = (i2 >> 3) & 63, nt = (i2 >> 9) & 3, q = (i2 >> 11) & 1, t = i2 >> 12;
      int co = nt * 16 + (lane & 15);
      int ci = q * 32 + ((lane >> 4) << 3) + j;
      ushort_t hs, ls;
      split_bf16(w2[(co * 64 + ci) * 9 + t], hs, ls);
      w2fh[i2] = hs; w2fl[i2] = ls;
    }
    int i3 = idx - 38912;
    if (i3 >= 0 && i3 < 384) {
      int b = i3 / 6, n = i3 % 6;
      float acc = 0.f;
      for (int t = 0; t < TT; t++) {
        const float* rp = rois + ((b * TT + t) * NOBJ + n) * 5;
        acc += (rp[4] - rp[2]) * 0.5f + (rp[3] - rp[1]) * 0.5f;
      }
      rbuf[i3] = acc * 0.125f;
    }
  } else {
    if (idx >= 1572864) return;
    int k = idx / 393216;
    int r = idx - k * 393216;
    ushort_t hs, ls;
    if (r < 196608) {
      int j = r & 7, lane = (r >> 3) & 63, kq = (r >> 9) & 7, nt = r >> 12;
      int kin = kq * 32 + ((lane >> 4) << 3) + j;
      int d = (nt & 15) * 16 + (lane & 15);
      int mat = nt >> 4;
      float v = (mat == 0) ? g_self_w[(k * 256 + d) * 256 + kin]
                           : g_rel_w[(k * 256 + d) * 512 + (mat == 2 ? 256 : 0) + kin];
      split_bf16(v, hs, ls);
      b1h[k * 196608 + r] = hs; b1l[k * 196608 + r] = ls;
    } else if (r < 262144) {
      int r2 = r - 196608;
      int j = r2 & 7, lane = (r2 >> 3) & 63, kq = (r2 >> 9) & 7, nt = r2 >> 12;
      int kin = kq * 32 + ((lane >> 4) << 3) + j;
      int d = nt * 16 + (lane & 15);
      split_bf16(g_aff_w[(k * 256 + d) * 256 + kin], hs, ls);
      bafh[k * 65536 + r2] = hs; bafl[k * 65536 + r2] = ls;
    } else {
      int r3 = r - 262144;
      int j = r3 & 7, lane = (r3 >> 3) & 63, kq = (r3 >> 9) & 15, nt = r3 >> 13;
      int kin = kq * 32 + ((lane >> 4) << 3) + j;
      int d = nt * 16 + (lane & 15);
      split_bf16(g_out_w[(k * 256 + d) * 512 + kin], hs, ls);
      bouh[k * 131072 + r3] = hs; boul[k * 131072 + r3] = ls;
    }
  }
}

// ---- fused conv1(fp32 vector) + conv2(split-bf16 MFMA) — round-4 verbatim ----
__global__ __launch_bounds__(512, 4) void convmf_kernel(const float* __restrict__ x,
                                                        const float* __restrict__ w1p,
                                                        const float* __restrict__ b1,
                                                        const ushort_t* __restrict__ w2fh,
                                                        const ushort_t* __restrict__ w2fl,
                                                        const float* __restrict__ b2,
                                                        float* __restrict__ feat2) {
  __shared__ __align__(16) float xs[3 * 11 * 72];
  __shared__ __align__(16) ushort_t f1h[5 * 34 * 72];
  __shared__ __align__(16) ushort_t f1l[5 * 34 * 72];
  int bx = blockIdx.x;
  int h = bx & 1;
  int band = (bx >> 1) & 15;
  int n = bx >> 5;
  int tid = threadIdx.x;
  int wave = __builtin_amdgcn_readfirstlane(tid >> 6);
  int lane = tid & 63;
  for (int i = tid; i < 3 * 11 * 72; i += 512) {
    int c = i % 72;
    int row = (i / 72) % 11;
    int ci = i / (72 * 11);
    int gr = 8 * band + row;
    int gc = h * 64 + c;
    float v = 0.f;
    if (gr < 128 && gc < 128 && c < 68) v = x[((n * 3 + ci) * 128 + gr) * 128 + gc];
    xs[(ci * 11 + row) * 72 + c] = v;
  }
  __syncthreads();
  int chb = wave * 8;
  int r0 = lane >> 4;
  int cp0 = lane & 15;
  int rB, xB;
  if (lane < 16) { rB = 4; xB = 4 * cp0; }
  else { int rr = lane - 16; rB = (rr < 5) ? rr : 0; xB = 64; }
  float a0[2][8] = {}; float aB[2][8] = {};
  for (int ci = 0; ci < 3; ci++) {
    #pragma unroll
    for (int ky = 0; ky < 3; ky++) {
      const float* wp = w1p + ((ci * 3 + ky) * 3) * 64 + chb;
      float wv[3][8];
      #pragma unroll
      for (int kx = 0; kx < 3; kx++)
        #pragma unroll
        for (int j = 0; j < 8; j++) wv[kx][j] = wp[kx * 64 + j];
      const float* x0 = &xs[(ci * 11 + 2 * r0 + ky) * 72 + 4 * cp0];
      float4 e4 = *(const float4*)x0; float e5 = x0[4];
      float xv[5] = {e4.x, e4.y, e4.z, e4.w, e5};
      #pragma unroll
      for (int c = 0; c < 2; c++)
        #pragma unroll
        for (int kx = 0; kx < 3; kx++) {
          float xx = xv[2 * c + kx];
          #pragma unroll
          for (int j = 0; j < 8; j++) a0[c][j] = fmaf(xx, wv[kx][j], a0[c][j]);
        }
      const float* x1 = &xs[(ci * 11 + 2 * rB + ky) * 72 + xB];
      float4 f4 = *(const float4*)x1; float f5 = x1[4];
      float yv[5] = {f4.x, f4.y, f4.z, f4.w, f5};
      #pragma unroll
      for (int c = 0; c < 2; c++)
        #pragma unroll
        for (int kx = 0; kx < 3; kx++) {
          float xx = yv[2 * c + kx];
          #pragma unroll
          for (int j = 0; j < 8; j++) aB[c][j] = fmaf(xx, wv[kx][j], aB[c][j]);
        }
    }
  }
  float bb[8];
  #pragma unroll
  for (int j = 0; j < 8; j++) bb[j] = b1[chb + j];
  int f1base = 4 * band;
  auto storecol = [&](int row, int col, const float* a, bool ok) {
    short8_t hv, lv;
    #pragma unroll
    for (int j = 0; j < 8; j++) {
      float v = ok ? fmaxf(a[j] + bb[j], 0.f) : 0.f;
      unsigned int bits = __float_as_uint(v);
      hv[j] = (short)(bits >> 16);
      float hf = __uint_as_float(bits & 0xFFFF0000u);
      lv[j] = (short)(__float_as_uint(v - hf) >> 16);
    }
    int base = (row * 34 + col) * 72 + chb;
    *(short8_t*)&f1h[base] = hv;
    *(short8_t*)&f1l[base] = lv;
  };
  storecol(r0, 2 * cp0,     a0[0], true);
  storecol(r0, 2 * cp0 + 1, a0[1], true);
  if (lane < 16) {
    bool ok4 = (f1base + 4) < 64;
    storecol(4, 2 * cp0,     aB[0], ok4);
    storecol(4, 2 * cp0 + 1, aB[1], ok4);
  } else if (lane < 21) {
    int rr = lane - 16;
    bool okc = (h == 0) && ((f1base + rr) < 64);
    storecol(rr, 32, aB[0], okc);
  }
  __syncthreads();
  int nt = wave & 3, mg = wave >> 2;
  f32x4 acc = {0.f, 0.f, 0.f, 0.f};
  #pragma unroll
  for (int t = 0; t < 9; t++) {
    int ky = t / 3, kx = t % 3;
    int col = 2 * (lane & 15) + kx;
    int row = 2 * mg + ky;
    int abase = (row * 34 + col) * 72 + ((lane >> 4) << 3);
    #pragma unroll
    for (int q = 0; q < 2; q++) {
      int widx = (((t * 2 + q) * 4 + nt) * 64 + lane) * 8;
      short8_t Bh = *(const short8_t*)(w2fh + widx);
      short8_t Bl = *(const short8_t*)(w2fl + widx);
      short8_t Ah = *(const short8_t*)&f1h[abase + q * 32];
      short8_t Al = *(const short8_t*)&f1l[abase + q * 32];
      acc = MFMA_BF16_16x16x32(Ah, Bh, acc, 0, 0, 0);
      acc = MFMA_BF16_16x16x32(Ah, Bl, acc, 0, 0, 0);
      acc = MFMA_BF16_16x16x32(Al, Bh, acc, 0, 0, 0);
    }
  }
  int co = nt * 16 + (lane & 15);
  int oy = band * 2 + mg;
  int ox = h * 16 + ((lane >> 4) << 2);
  float bv = b2[co];
  float4 o;
  o.x = fmaxf(acc[0] + bv, 0.f);
  o.y = fmaxf(acc[1] + bv, 0.f);
  o.z = fmaxf(acc[2] + bv, 0.f);
  o.w = fmaxf(acc[3] + bv, 0.f);
  *(float4*)&feat2[((n * 64 + co) * 32 + oy) * 32 + ox] = o;
}

// ---- fused head: roi_align + fc0 + emb + fc1c + red -> obj. 192 blocks × 8 rows. ----
__global__ __launch_bounds__(512) void head_kernel(const float* __restrict__ feat2,
                                                   const float* __restrict__ rois,
                                                   const float* __restrict__ src_coor,
                                                   const float* __restrict__ fc0T,
                                                   const float* __restrict__ fc0_b,
                                                   const float* __restrict__ fc0c_w,
                                                   const float* __restrict__ fc0c_b,
                                                   const float* __restrict__ fc1cT,
                                                   const float* __restrict__ fc1c_b,
                                                   const float* __restrict__ redT,
                                                   const float* __restrict__ red_b,
                                                   float* __restrict__ obj) {
  __shared__ __align__(16) float sh[14336];   // 56 KB
  float* poolL = sh;            // 8×1024
  float* catL  = sh + 8192;     // 8×512
  float* embL  = sh + 12288;    // 8×256
  int r0 = blockIdx.x * 8;
  int tid = threadIdx.x;
  // ROI align for this block's 8 rows
  for (int it = 0; it < 16; it++) {
    int o = it * 512 + tid;
    int lr = o >> 10, po = o & 1023;
    int px = po & 3, py = (po >> 2) & 3, c = po >> 4;
    const float* rp = rois + (r0 + lr) * 5;
    int bi = (int)rp[0];
    float x1 = rp[1] * 0.25f, y1 = rp[2] * 0.25f, x2 = rp[3] * 0.25f, y2 = rp[4] * 0.25f;
    float bw = fmaxf(x2 - x1, 1.0f) * 0.25f;
    float bh = fmaxf(y2 - y1, 1.0f) * 0.25f;
    float sx = x1 + bw * (px + 0.5f);
    float sy = y1 + bh * (py + 0.5f);
    float x0f = fminf(fmaxf(floorf(sx), 0.f), 31.f);
    float y0f = fminf(fmaxf(floorf(sy), 0.f), 31.f);
    float lx = fminf(fmaxf(sx - x0f, 0.f), 1.f);
    float ly = fminf(fmaxf(sy - y0f, 0.f), 1.f);
    int ix0 = (int)x0f, iy0 = (int)y0f;
    int ix1 = min(ix0 + 1, 31), iy1 = min(iy0 + 1, 31);
    const float* f = feat2 + (bi * 64 + c) * 1024;
    float v00 = f[iy0 * 32 + ix0], v01 = f[iy0 * 32 + ix1];
    float v10 = f[iy1 * 32 + ix0], v11 = f[iy1 * 32 + ix1];
    poolL[o] = v00 * (1 - ly) * (1 - lx) + v01 * (1 - ly) * lx + v10 * ly * (1 - lx) +
               v11 * ly * lx;
  }
  // emb
  for (int idx = tid; idx < 2048; idx += 512) {
    int rr = idx >> 8, cc = idx & 255;
    const float* cp = src_coor + (size_t)(r0 + rr) * 2;
    embL[idx] = fmaxf(cp[0] * fc0c_w[cc * 2] + cp[1] * fc0c_w[cc * 2 + 1] + fc0c_b[cc], 0.f);
  }
  __syncthreads();
  int d = tid & 255;
  int half = __builtin_amdgcn_readfirstlane(tid >> 8);
  // fc0: K=1024
  {
    float acc[4] = {};
    const float* asb = poolL + half * 4 * 1024;
    for (int kq = 0; kq < 256; kq++) {
      float4 wv = *(const float4*)(fc0T + kq * 1024 + d * 4);
      #pragma unroll
      for (int rr = 0; rr < 4; rr++) {
        float4 a4 = *(const float4*)(asb + rr * 1024 + kq * 4);
        FMA4(acc[rr], a4, wv);
      }
    }
    float bv = fc0_b[d];
    #pragma unroll
    for (int rr = 0; rr < 4; rr++)
      catL[(half * 4 + rr) * 512 + d] = fmaxf(acc[rr] + bv, 0.f);
  }
  // fc1c: K=256
  {
    float acc[4] = {};
    const float* asb = embL + half * 4 * 256;
    for (int kq = 0; kq < 64; kq++) {
      float4 wv = *(const float4*)(fc1cT + kq * 1024 + d * 4);
      #pragma unroll
      for (int rr = 0; rr < 4; rr++) {
        float4 a4 = *(const float4*)(asb + rr * 256 + kq * 4);
        FMA4(acc[rr], a4, wv);
      }
    }
    float bv = fc1c_b[d];
    #pragma unroll
    for (int rr = 0; rr < 4; rr++)
      catL[(half * 4 + rr) * 512 + 256 + d] = fmaxf(acc[rr] + bv, 0.f);
  }
  __syncthreads();
  // red: K=512
  {
    float acc[4] = {};
    const float* asb = catL + half * 4 * 512;
    for (int kq = 0; kq < 128; kq++) {
      float4 wv = *(const float4*)(redT + kq * 1024 + d * 4);
      #pragma unroll
      for (int rr = 0; rr < 4; rr++) {
        float4 a4 = *(const float4*)(asb + rr * 512 + kq * 4);
        FMA4(acc[rr], a4, wv);
      }
    }
    float bv = red_b[d];
    #pragma unroll
    for (int rr = 0; rr < 4; rr++)
      obj[(r0 + half * 4 + rr) * 256 + d] = fmaxf(acc[rr] + bv, 0.f);
  }
}

// ---- internet via MFMA, with inline agg(j-1)+dec in k=3 blocks. 128 blocks. ----
__global__ __launch_bounds__(512) void internet_mfma(
    int j, const float* __restrict__ obj, float* __restrict__ sbuf,
    const float* __restrict__ src_coor, float* __restrict__ dout,
    const float* __restrict__ rbuf, const float* __restrict__ cs_r, float* __restrict__ cs_w,
    const float* __restrict__ aggT, const float* __restrict__ agg_b,
    const ushort_t* __restrict__ b1h, const ushort_t* __restrict__ b1l,
    const ushort_t* __restrict__ bafh, const ushort_t* __restrict__ bafl,
    const ushort_t* __restrict__ bouh, const ushort_t* __restrict__ boul,
    const float* __restrict__ self_b, const float* __restrict__ rel_b,
    const float* __restrict__ aff_b, const float* __restrict__ out_b,
    const float* __restrict__ decw, const float* __restrict__ decb) {
  // smem liveness plan (62784 B total):
  //  agg phase (k=3,j>=1): csL [0,49152), snL [49152,61440)
  //  P0 splits:            sAh [0,6336), sAl [6336,12672)   (csL dead; snL read)
  //  P1/P2:                bufA [12672,50112)                (snL dead)
  //  P2 out:               hAh [50112,56448), hAl [56448,62784)
  //  P3 out:               aAh [12672,19008), aAl [19008,25344)  (bufA dead)
  __shared__ __align__(16) char smem[62784];
  __shared__ float coor_lds[2][12], r_lds[2][6], mw[2][6][8];
  float* csL = (float*)smem;
  float* snL = (float*)(smem + 49152);
  ushort_t* sAh = (ushort_t*)smem;
  ushort_t* sAl = (ushort_t*)(smem + 6336);
  float* bufA = (float*)(smem + 12672);
  ushort_t* hAh = (ushort_t*)(smem + 50112);
  ushort_t* hAl = (ushort_t*)(smem + 56448);
  ushort_t* aAh = (ushort_t*)(smem + 12672);
  ushort_t* aAl = (ushort_t*)(smem + 19008);

  int bx = blockIdx.x;
  int k = __builtin_amdgcn_readfirstlane((bx & 7) >> 1);
  int pb = __builtin_amdgcn_readfirstlane(((bx & 1) << 4) | (bx >> 3));   // 0..31
  int tid = threadIdx.x;
  int wave = __builtin_amdgcn_readfirstlane(tid >> 6);
  int lane = tid & 63;
  int m15 = lane & 15, quad = lane >> 4;
  int mrow = (m15 < 12) ? m15 : 0;
  int sl = j + k;
  bool aggcase = (k == 3) && (j >= 1);
  const float* srow[2] = {nullptr, nullptr};
  if (!aggcase) {
    #pragma unroll
    for (int bq = 0; bq < 2; bq++) {
      int b = pb * 2 + bq;
      srow[bq] = (sl < 4) ? (obj + (b * 4 + sl) * 1536) : (sbuf + ((sl - 4) * 64 + b) * 1536);
    }
  }
  if (tid < 12) r_lds[tid / 6][tid % 6] = rbuf[(pb * 2 + tid / 6) * 6 + tid % 6];

  if (aggcase) {
    // stage cs[j-1] rows for 2 batches
    for (int idx = tid; idx < 12288; idx += 512) {
      int row = idx >> 10, e = idx & 1023;
      int bq = (row >= 6) ? 1 : 0, i = row - bq * 6;
      csL[idx] = cs_r[((pb * 2 + bq) * 6 + i) * 1024 + e];
    }
    __syncthreads();
    // agg: sn[j-1] = cs . aggW^T + b (no relu)
    for (int s = 0; s < 6; s++) {
      int o = s * 512 + tid;          // 3072 outputs; d = tid&255 const per thread
      int row = o >> 8, dloc = o & 255;
      float acc = 0.f;
      const float* wp = aggT + dloc * 4;
      const float* ap = csL + row * 1024;
      for (int kq = 0; kq < 256; kq++) {
        float4 wv = *(const float4*)(wp + kq * 1024);
        float4 a4 = *(const float4*)(ap + kq * 4);
        FMA4(acc, a4, wv);
      }
      float v = acc + agg_b[dloc];
      snL[o] = v;
      int bq = (row >= 6) ? 1 : 0, i = row - bq * 6;
      sbuf[(((j - 1) * 64 + (pb * 2 + bq)) * 6 + i) * 256 + dloc] = v;
    }
    __syncthreads();
    // dec(sn[j-1]) -> dout row j-1 + coor
    if (tid < 384) {
      int lane8 = tid & 7;
      int p = tid >> 3;              // 0..47
      int bq = p / 24, pp = p % 24;
      int i = pp >> 2, o = pp & 3;
      float a2 = 0.f;
      #pragma unroll
      for (int m = 0; m < 32; m++) {
        int dd = lane8 + m * 8;
        a2 = fmaf(snL[(bq * 6 + i) * 256 + dd], decw[o * 256 + dd], a2);
      }
      a2 += __shfl_down(a2, 4, 8);
      a2 += __shfl_down(a2, 2, 8);
      a2 += __shfl_down(a2, 1, 8);
      if (lane8 == 0) {
        float val = a2 + decb[o];
        dout[(((pb * 2 + bq) * 8 + (j - 1)) * 6 + i) * 4 + o] = val;
        if (o >= 2) coor_lds[bq][i * 2 + (o - 2)] = val;
      }
    }
  } else {
    if (tid < 24) {
      int bq = tid / 12, t12 = tid % 12;
      int i = t12 >> 1, c = t12 & 1;
      int b = pb * 2 + bq;
      coor_lds[bq][t12] = (sl < 4) ? src_coor[((b * 4 + sl) * 6 + i) * 2 + c]
                                   : dout[((b * 8 + (sl - 4)) * 6 + i) * 4 + 2 + c];
    }
  }
  __syncthreads();
  // split s -> sA (from snL for aggcase, global srow otherwise)
  for (int pos = tid; pos < 3072; pos += 512) {
    int row = pos >> 8, dd = pos & 255;
    int bq = (row >= 6) ? 1 : 0, i = row - bq * 6;
    float v = aggcase ? snL[row * 256 + dd] : srow[bq][i * 256 + dd];
    ushort_t hs, ls;
    split_bf16(v, hs, ls);
    sAh[row * 264 + dd] = hs;
    sAl[row * 264 + dd] = ls;
  }
  __syncthreads();
  // mask
  if (tid < 72) {
    int bq = tid / 36, rest = tid % 36;
    int i = rest / 6, jj = rest % 6;
    float dx = coor_lds[bq][i * 2] - coor_lds[bq][jj * 2];
    float dy = coor_lds[bq][i * 2 + 1] - coor_lds[bq][jj * 2 + 1];
    float dist = sqrtf(dx * dx + dy * dy);
    mw[bq][i][jj] = (i != jj && dist <= r_lds[bq][i] + r_lds[bq][jj]) ? 1.f : 0.f;
  }
  // P1: stage-1 MFMA (self|u|v as one N=768 GEMM)
  {
    f32x4 acc1[6] = {};
    const ushort_t* b1hk = b1h + (size_t)k * 196608;
    const ushort_t* b1lk = b1l + (size_t)k * 196608;
    for (int kq = 0; kq < 8; kq++) {
      int aoff = mrow * 264 + kq * 32 + quad * 8;
      short8_t Ah = *(const short8_t*)(sAh + aoff);
      short8_t Al = *(const short8_t*)(sAl + aoff);
      #pragma unroll
      for (int tt = 0; tt < 6; tt++) {
        int t = wave * 6 + tt;
        int bi = ((t * 8 + kq) * 64 + lane) * 8;
        short8_t Bh = *(const short8_t*)(b1hk + bi);
        short8_t Bl = *(const short8_t*)(b1lk + bi);
        acc1[tt] = MFMA_BF16_16x16x32(Ah, Bh, acc1[tt], 0, 0, 0);
        acc1[tt] = MFMA_BF16_16x16x32(Ah, Bl, acc1[tt], 0, 0, 0);
        acc1[tt] = MFMA_BF16_16x16x32(Al, Bh, acc1[tt], 0, 0, 0);
      }
    }
    #pragma unroll
    for (int tt = 0; tt < 6; tt++) {
      int t = wave * 6 + tt;
      int mat = t >> 4, ntm = t & 15;
      float* buf = bufA + mat * 3120;
      #pragma unroll
      for (int reg = 0; reg < 4; reg++) {
        int m = quad * 4 + reg;
        if (m < 12) buf[m * 260 + ntm * 16 + m15] = acc1[tt][reg];
      }
    }
  }
  __syncthreads();
  // P2: h = as + self_b + cnt*(au+rel_b) + sum_j mw*av ; split -> hA
  for (int rr = 0; rr < 6; rr++) {
    int pos = rr * 512 + tid;
    int row = pos >> 8, d = pos & 255;
    int bq = (row >= 6) ? 1 : 0, i = row - bq * 6;
    float as = bufA[row * 260 + d];
    float au = bufA[3120 + row * 260 + d];
    float cnt = mw[bq][i][0] + mw[bq][i][1] + mw[bq][i][2] + mw[bq][i][3] + mw[bq][i][4] +
                mw[bq][i][5];
    float hsum = as + self_b[k * 256 + d] + cnt * (au + rel_b[k * 256 + d]);
    #pragma unroll
    for (int jj = 0; jj < 6; jj++)
      hsum = fmaf(mw[bq][i][jj], bufA[6240 + (bq * 6 + jj) * 260 + d], hsum);
    ushort_t hs, ls;
    split_bf16(hsum, hs, ls);
    hAh[row * 264 + d] = hs;
    hAl[row * 264 + d] = ls;
  }
  __syncthreads();
  // P3: aff MFMA -> relu -> aA
  {
    f32x4 acc2[2] = {};
    const ushort_t* bhk = bafh + (size_t)k * 65536;
    const ushort_t* blk = bafl + (size_t)k * 65536;
    for (int kq = 0; kq < 8; kq++) {
      int aoff = mrow * 264 + kq * 32 + quad * 8;
      short8_t Ah = *(const short8_t*)(hAh + aoff);
      short8_t Al = *(const short8_t*)(hAl + aoff);
      #pragma unroll
      for (int tt = 0; tt < 2; tt++) {
        int t = wave * 2 + tt;
        int bi = ((t * 8 + kq) * 64 + lane) * 8;
        short8_t Bh = *(const short8_t*)(bhk + bi);
        short8_t Bl = *(const short8_t*)(blk + bi);
        acc2[tt] = MFMA_BF16_16x16x32(Ah, Bh, acc2[tt], 0, 0, 0);
        acc2[tt] = MFMA_BF16_16x16x32(Ah, Bl, acc2[tt], 0, 0, 0);
        acc2[tt] = MFMA_BF16_16x16x32(Al, Bh, acc2[tt], 0, 0, 0);
      }
    }
    __syncthreads();   // bufA fully read in P2; safe to overwrite with aA
    #pragma unroll
    for (int tt = 0; tt < 2; tt++) {
      int t = wave * 2 + tt;
      int d = t * 16 + m15;
      float bias = aff_b[k * 256 + d];
      #pragma unroll
      for (int reg = 0; reg < 4; reg++) {
        int m = quad * 4 + reg;
        if (m < 12) {
          float v = fmaxf(acc2[tt][reg] + bias, 0.f);
          ushort_t hs, ls;
          split_bf16(v, hs, ls);
          aAh[m * 264 + d] = hs;
          aAl[m * 264 + d] = ls;
        }
      }
    }
  }
  __syncthreads();
  // P4: out MFMA over K=512 ([a|s]) -> relu -> cs_w
  {
    f32x4 acc3[2] = {};
    const ushort_t* bhk = bouh + (size_t)k * 131072;
    const ushort_t* blk = boul + (size_t)k * 131072;
    for (int kq = 0; kq < 16; kq++) {
      const ushort_t* Abh = (kq < 8) ? (aAh + mrow * 264 + kq * 32)
                                     : (sAh + mrow * 264 + (kq - 8) * 32);
      const ushort_t* Abl = (kq < 8) ? (aAl + mrow * 264 + kq * 32)
                                     : (sAl + mrow * 264 + (kq - 8) * 32);
      short8_t Ah = *(const short8_t*)(Abh + quad * 8);
      short8_t Al = *(const short8_t*)(Abl + quad * 8);
      #pragma unroll
      for (int tt = 0; tt < 2; tt++) {
        int t = wave * 2 + tt;
        int bi = ((t * 16 + kq) * 64 + lane) * 8;
        short8_t Bh = *(const short8_t*)(bhk + bi);
        short8_t Bl = *(const short8_t*)(blk + bi);
        acc3[tt] = MFMA_BF16_16x16x32(Ah, Bh, acc3[tt], 0, 0, 0);
        acc3[tt] = MFMA_BF16_16x16x32(Ah, Bl, acc3[tt], 0, 0, 0);
        acc3[tt] = MFMA_BF16_16x16x32(Al, Bh, acc3[tt], 0, 0, 0);
      }
    }
    #pragma unroll
    for (int tt = 0; tt < 2; tt++) {
      int t = wave * 2 + tt;
      int d = t * 16 + m15;
      float bias = out_b[k * 256 + d];
      #pragma unroll
      for (int reg = 0; reg < 4; reg++) {
        int m = quad * 4 + reg;
        if (m < 12) {
          int bq = (m >= 6) ? 1 : 0, i = m - bq * 6;
          int b = pb * 2 + bq;
          cs_w[(b * 6 + i) * 1024 + k * 256 + d] = fmaxf(acc3[tt][reg] + bias, 0.f);
        }
      }
    }
  }
}

// ---- final: agg(cs[7]) + dec -> dout rows 7 ----
__global__ __launch_bounds__(512) void declast_kernel(const float* __restrict__ cs_r,
                                                      const float* __restrict__ aggT,
                                                      const float* __restrict__ agg_b,
                                                      const float* __restrict__ decw,
                                                      const float* __restrict__ decb,
                                                      float* __restrict__ dout) {
  __shared__ __align__(16) float csL[6 * 1024];
  __shared__ float snL[6 * 256];
  int b = blockIdx.x;
  int tid = threadIdx.x;
  for (int idx = tid; idx < 6144; idx += 512) csL[idx] = cs_r[b * 6144 + idx];
  __syncthreads();
  for (int s = 0; s < 3; s++) {
    int o = s * 512 + tid;
    int row = o >> 8, d = o & 255;
    float acc = 0.f;
    const float* wp = aggT + d * 4;
    const float* ap = csL + row * 1024;
    for (int kq = 0; kq < 256; kq++) {
      float4 wv = *(const float4*)(wp + kq * 1024);
      float4 a4 = *(const float4*)(ap + kq * 4);
      FMA4(acc, a4, wv);
    }
    snL[o] = acc + agg_b[d];
  }
  __syncthreads();
  if (tid < 192) {
    int lane8 = tid & 7;
    int p = tid >> 3;     // 0..23
    int i = p >> 2, o = p & 3;
    float a2 = 0.f;
    #pragma unroll
    for (int m = 0; m < 32; m++) {
      int dd = lane8 + m * 8;
      a2 = fmaf(snL[i * 256 + dd], decw[o * 256 + dd], a2);
    }
    a2 += __shfl_down(a2, 4, 8);
    a2 += __shfl_down(a2, 2, 8);
    a2 += __shfl_down(a2, 1, 8);
    if (lane8 == 0) dout[((b * 8 + 7) * 6 + i) * 4 + o] = a2 + decb[o];
  }
}

extern "C" void kernel_launch(void* const* d_in, const int* in_sizes, int n_in,
                              void* d_out, int out_size, void* d_ws, size_t ws_size,
                              hipStream_t stream) {
  const float* x        = (const float*)d_in[0];
  const float* rois     = (const float*)d_in[1];
  const float* src_coor = (const float*)d_in[2];
  const float* w_conv1  = (const float*)d_in[3];
  const float* b_conv1  = (const float*)d_in[4];
  const float* w_conv2  = (const float*)d_in[5];
  const float* b_conv2  = (const float*)d_in[6];
  const float* fc0_w    = (const float*)d_in[7];
  const float* fc0_b    = (const float*)d_in[8];
  const float* fc0c_w   = (const float*)d_in[9];
  const float* fc0c_b   = (const float*)d_in[10];
  const float* fc1c_w   = (const float*)d_in[11];
  const float* fc1c_b   = (const float*)d_in[12];
  const float* red_w    = (const float*)d_in[13];
  const float* red_b    = (const float*)d_in[14];
  const float* g_self_w = (const float*)d_in[15];
  const float* g_self_b = (const float*)d_in[16];
  const float* g_rel_w  = (const float*)d_in[17];
  const float* g_rel_b  = (const float*)d_in[18];
  const float* g_aff_w  = (const float*)d_in[19];
  const float* g_aff_b  = (const float*)d_in[20];
  const float* g_out_w  = (const float*)d_in[21];
  const float* g_out_b  = (const float*)d_in[22];
  const float* agg_w    = (const float*)d_in[23];
  const float* agg_b    = (const float*)d_in[24];
  const float* dec_w    = (const float*)d_in[25];
  const float* dec_b    = (const float*)d_in[26];
  float* out = (float*)d_out;

  float* ws = (float*)d_ws;
  size_t off = 0;
  auto alloc = [&](size_t nf) { float* p = ws + off; off += (nf + 63) & ~(size_t)63; return p; };
  float* feat2 = alloc(16777216);   // (256,64,32,32)
  float* obj   = alloc(393216);
  float* sbuf  = alloc(786432);
  float* cs0   = alloc(393216);
  float* cs1   = alloc(393216);
  float* rbuf  = alloc(384);
  float* fc0T  = alloc(262144);
  float* fc1cT = alloc(65536);
  float* redT  = alloc(131072);
  float* aggT  = alloc(262144);
  float* w1p   = alloc(1728);
  ushort_t* w2fh = (ushort_t*)alloc(18432);
  ushort_t* w2fl = (ushort_t*)alloc(18432);
  ushort_t* b1h  = (ushort_t*)alloc(393216);
  ushort_t* b1l  = (ushort_t*)alloc(393216);
  ushort_t* bafh = (ushort_t*)alloc(131072);
  ushort_t* bafl = (ushort_t*)alloc(131072);
  ushort_t* bouh = (ushort_t*)alloc(262144);
  ushort_t* boul = (ushort_t*)alloc(262144);
  // total ≈ 20.8M floats ≈ 83 MB

  MatDescs md;
  md.m[0] = {fc0_w,  fc0T,  10, 1024, 0};
  md.m[1] = {fc1c_w, fc1cT, 8,  256,  0};
  md.m[2] = {red_w,  redT,  9,  512,  0};
  md.m[3] = {agg_w,  aggT,  10, 1024, 0};

  prep_all<<<dim3(6144, 6), dim3(256), 0, stream>>>(md, w_conv1, w_conv2, rois, w1p, w2fh, w2fl,
      rbuf, g_self_w, g_rel_w, g_aff_w, g_out_w, b1h, b1l, bafh, bafl, bouh, boul);
  convmf_kernel<<<dim3(8192), dim3(512), 0, stream>>>(x, w1p, b_conv1, w2fh, w2fl, b_conv2, feat2);
  head_kernel<<<dim3(192), dim3(512), 0, stream>>>(feat2, rois, src_coor, fc0T, fc0_b, fc0c_w,
      fc0c_b, fc1cT, fc1c_b, redT, red_b, obj);
  for (int j = 0; j < 8; j++) {
    const float* cs_r = (j & 1) ? cs0 : cs1;
    float* cs_w = (j & 1) ? cs1 : cs0;
    internet_mfma<<<dim3(128), dim3(512), 0, stream>>>(j, obj, sbuf, src_coor, out, rbuf,
        cs_r, cs_w, aggT, agg_b, b1h, b1l, bafh, bafl, bouh, boul,
        g_self_b, g_rel_b, g_aff_b, g_out_b, dec_w, dec_b);
  }
  declast_kernel<<<dim3(64), dim3(512), 0, stream>>>(cs1, aggT, agg_b, dec_w, dec_b, out);
  (void)in_sizes; (void)n_in; (void)out_size; (void)ws_size;
}